// Round 18
// baseline (209.321 us; speedup 1.0000x reference)
//
#include <hip/hip_runtime.h>

#define ND 256       // embedding dim
#define NK 512       // centroids
#define LM2 0.0625f  // lambda^2
#define DELTA 0.25f  // approx top-2 gap below this -> exact fp32 rescore

typedef _Float16 f16x8 __attribute__((ext_vector_type(8)));
typedef float f32x4 __attribute__((ext_vector_type(4)));
typedef unsigned short u16x8 __attribute__((ext_vector_type(8)));
typedef unsigned short u16x4 __attribute__((ext_vector_type(4)));

// async 16B global->LDS (zero VGPR staging). LDS dest is wave-uniform base
// (HW adds lane*16); global src is per-lane.
#define GLD16(GSRC, LDST)                                                      \
    __builtin_amdgcn_global_load_lds(                                         \
        (const __attribute__((address_space(1))) void*)(GSRC),                \
        (__attribute__((address_space(3))) void*)(LDST), 16, 0, 0)

// ---------------- prep: csq[k] + fp16 centroids in per-64col-panel frag order --
// Cf layout: [panel 8][krow 32][col 64][8], krow = (d>>5)*4 + ((d>>3)&3).
// 16B granule = one lane's B-frag slice (measured 0 bank conflicts r4-r17).
__global__ __launch_bounds__(64) void prep_kernel(const float* __restrict__ Cg,
                                                  float* __restrict__ csq,
                                                  unsigned short* __restrict__ Cf) {
    const int k = blockIdx.x, lane = threadIdx.x;
    float4 v = *(const float4*)(Cg + (size_t)k * ND + lane * 4);
    float s = v.x * v.x + v.y * v.y + v.z * v.z + v.w * v.w;
#pragma unroll
    for (int m = 1; m <= 32; m <<= 1) s += __shfl_xor(s, m, 64);
    if (lane == 0) csq[k] = s;
    u16x4 h;
    h[0] = __builtin_bit_cast(unsigned short, (_Float16)v.x);
    h[1] = __builtin_bit_cast(unsigned short, (_Float16)v.y);
    h[2] = __builtin_bit_cast(unsigned short, (_Float16)v.z);
    h[3] = __builtin_bit_cast(unsigned short, (_Float16)v.w);
    const int panel = k >> 6, col = k & 63;
    const int krow = (lane >> 3) * 4 + ((lane >> 1) & 3);  // d0 = lane*4
    const size_t idx = ((size_t)panel << 14) + ((((size_t)krow << 6) + col) << 3) + ((lane & 1) << 2);
    *(u16x4*)(Cf + idx) = h;
}

// ---------------- main: 4 waves x 64 rows — ONE generation, 4x B-reuse -------
// grid 512 x 256 thr: 256 rows/block, all blocks resident. Each B-frag
// ds_read_b128 feeds FOUR MFMAs (m=0..3) -> chip LDS-read volume 524 MB
// (10.2 us floor, below the 16.6 us MFMA floor). Register plan follows r6's
// proven no-spill shape: heavy AGPR (acc[4][4]=64), arch ~190 (A=128 + keys 32).
// B panels dbuf'd via gload_lds, ONE barrier/panel; u32 top-2 keys; exact
// rescore net in combine. Spill tripwire: WRITE_SIZE.
__global__ __launch_bounds__(256, 2) void kmeans_mfma(
    const float* __restrict__ E, const unsigned short* __restrict__ Cf,
    const float* __restrict__ csq, uint2* __restrict__ partials,
    float* __restrict__ e2s) {
    __shared__ unsigned short Bbuf[2][16384];  // 2 x 32 KB

    const int tid = threadIdx.x;
    const int lane = tid & 63, wid = tid >> 6;  // wid 0..3
    const int l15 = lane & 15, l4 = lane >> 4;
    const int rowbase = blockIdx.x << 8;  // 256 rows/block
    const int wrow = rowbase + wid * 64;  // 64 rows/wave

    // ---- issue panel 0 staging (flies during A-stage); 8 slots per wave ----
#pragma unroll
    for (int i = 0; i < 8; ++i)
        GLD16(Cf + (((size_t)(wid * 8 + i) * 64 + lane) << 3),
              &Bbuf[0][(size_t)(wid * 8 + i) << 9]);

    // ---- A stage: rows wrow + m*16 + l15 (m=0..3), chunks of 4 ks ----
    f16x8 A[4][8];  // [m][ks], 128 VGPR
    float e2 = 0.f;
#pragma unroll
    for (int m = 0; m < 4; ++m) {
        const float* ap = E + (size_t)(wrow + m * 16 + l15) * ND + l4 * 8;
#pragma unroll
        for (int half = 0; half < 2; ++half) {
            float4 t[8];
#pragma unroll
            for (int q = 0; q < 4; ++q) {
                t[q * 2]     = *(const float4*)(ap + (half * 4 + q) * 32);
                t[q * 2 + 1] = *(const float4*)(ap + (half * 4 + q) * 32 + 4);
            }
#pragma unroll
            for (int q = 0; q < 4; ++q) {
                float4 v0 = t[q * 2], v1 = t[q * 2 + 1];
                e2 += v0.x * v0.x + v0.y * v0.y + v0.z * v0.z + v0.w * v0.w +
                      v1.x * v1.x + v1.y * v1.y + v1.z * v1.z + v1.w * v1.w;
                u16x8 h;
                h[0] = __builtin_bit_cast(unsigned short, (_Float16)v0.x);
                h[1] = __builtin_bit_cast(unsigned short, (_Float16)v0.y);
                h[2] = __builtin_bit_cast(unsigned short, (_Float16)v0.z);
                h[3] = __builtin_bit_cast(unsigned short, (_Float16)v0.w);
                h[4] = __builtin_bit_cast(unsigned short, (_Float16)v1.x);
                h[5] = __builtin_bit_cast(unsigned short, (_Float16)v1.y);
                h[6] = __builtin_bit_cast(unsigned short, (_Float16)v1.z);
                h[7] = __builtin_bit_cast(unsigned short, (_Float16)v1.w);
                A[m][half * 4 + q] = __builtin_bit_cast(f16x8, h);
            }
        }
    }

    unsigned k1[4][4], k2[4][4];
#pragma unroll
    for (int m = 0; m < 4; ++m)
#pragma unroll
        for (int j = 0; j < 4; ++j) { k1[m][j] = 0u; k2[m][j] = 0u; }

    const unsigned ckb = (unsigned)(NK - 1) - (unsigned)l15;  // 511 - l15

#pragma unroll 1
    for (int p = 0; p < 8; ++p) {
        __syncthreads();  // drains own vmcnt: panel p staged; buf[(p+1)&1] free
        if (p < 7) {      // issue next panel (lands during this panel's compute)
            const unsigned short* gsrc = Cf + ((size_t)(p + 1) << 14);
            unsigned short* ldst = (unsigned short*)Bbuf[(p + 1) & 1];
#pragma unroll
            for (int i = 0; i < 8; ++i)
                GLD16(gsrc + (((size_t)(wid * 8 + i) * 64 + lane) << 3),
                      &ldst[(size_t)(wid * 8 + i) << 9]);
        }
        float csp[4];
#pragma unroll
        for (int n = 0; n < 4; ++n) csp[n] = csq[(p << 6) + n * 16 + l15];

        // compute panel: 8 ks x {4 B-frag ds_read_b128, 16 MFMA (bf reused m=0..3)}
        const unsigned short* cur = Bbuf[p & 1];
        f32x4 acc[4][4] = {};
#pragma unroll
        for (int ks = 0; ks < 8; ++ks) {
#pragma unroll
            for (int n = 0; n < 4; ++n) {
                const u16x8 bfr =
                    *(const u16x8*)&cur[(size_t)((((ks << 2) + l4) << 6) + n * 16 + l15) << 3];
                const f16x8 bf = __builtin_bit_cast(f16x8, bfr);
#pragma unroll
                for (int m = 0; m < 4; ++m)
                    acc[m][n] = __builtin_amdgcn_mfma_f32_16x16x32_f16(A[m][ks], bf, acc[m][n], 0, 0, 0);
            }
        }
        // fold panel into running per-lane u32 top-2 keys
        // key = mono(score) & ~511 | (511 - col); chop err ~5e-3 << DELTA
#pragma unroll
        for (int m = 0; m < 4; ++m)
#pragma unroll
            for (int j = 0; j < 4; ++j)
#pragma unroll
                for (int n = 0; n < 4; ++n) {
                    const float s = fmaf(-2.f, acc[m][n][j], csp[n]);
                    const unsigned b = __builtin_bit_cast(unsigned, s);
                    const unsigned mono = b ^ ((unsigned)((int)b >> 31) | 0x80000000u);
                    const unsigned key = (mono & 0xFFFFFE00u) | (ckb - (unsigned)((p << 6) + n * 16));
                    const unsigned mn = min(k1[m][j], key);
                    k1[m][j] = max(k1[m][j], key);
                    k2[m][j] = max(k2[m][j], mn);
                }
    }

    // ---- single end-of-block merge across the 16 l15 lanes ----
#pragma unroll
    for (int m = 0; m < 4; ++m)
#pragma unroll
        for (int j = 0; j < 4; ++j) {
            unsigned a = k1[m][j], b2 = k2[m][j];
#pragma unroll
            for (int mk = 1; mk <= 8; mk <<= 1) {
                const unsigned oa = __shfl_xor(a, mk, 64);
                const unsigned ob = __shfl_xor(b2, mk, 64);
                const unsigned mn = min(a, oa);
                a = max(a, oa);
                b2 = max(max(b2, ob), mn);
            }
            if (l15 == 0) {
                const int row = wrow + m * 16 + l4 * 4 + j;
                uint2 o;
                o.x = a;
                o.y = b2;
                partials[row] = o;
            }
        }

    // ---- e2 partial (each row counted exactly once chip-wide; one gen) ----
#pragma unroll
    for (int mk = 1; mk <= 32; mk <<= 1) e2 += __shfl_xor(e2, mk, 64);
    if (lane == 0) e2s[blockIdx.x * 4 + wid] = e2;
}

// ---------------- combine: decode top-2 keys, rescore near-ties --------------
__global__ __launch_bounds__(256) void combine_kernel(
    const uint2* __restrict__ partials, const float* __restrict__ csq,
    const float* __restrict__ E, const float* __restrict__ Cg,
    float* __restrict__ out, float* __restrict__ sum2) {
    const int n = blockIdx.x * 256 + threadIdx.x;
    const uint2 kk = partials[n];
    const unsigned m1 = kk.x & 0xFFFFFE00u;
    float v1 = __builtin_bit_cast(float, (m1 & 0x80000000u) ? (m1 ^ 0x80000000u) : ~m1);
    int i1 = (int)(NK - 1) - (int)(kk.x & 511u);
    const unsigned m2 = kk.y & 0xFFFFFE00u;
    const float v2 = __builtin_bit_cast(float, (m2 & 0x80000000u) ? (m2 ^ 0x80000000u) : ~m2);
    const int i2 = (int)(NK - 1) - (int)(kk.y & 511u);

    if (v1 - v2 <= DELTA) {  // near-tie: exact fp32 rescore of both candidates
        const float* e = E + (size_t)n * ND;
        const float* c1p = Cg + (size_t)i1 * ND;
        const float* c2p = Cg + (size_t)i2 * ND;
        float d1 = 0.f, d2 = 0.f;
        for (int d = 0; d < ND; d += 4) {
            float4 ev = *(const float4*)(e + d);
            float4 cv1 = *(const float4*)(c1p + d);
            float4 cv2 = *(const float4*)(c2p + d);
            d1 += ev.x * cv1.x + ev.y * cv1.y + ev.z * cv1.z + ev.w * cv1.w;
            d2 += ev.x * cv2.x + ev.y * cv2.y + ev.z * cv2.z + ev.w * cv2.w;
        }
        const float s1 = csq[i1] - 2.f * d1;
        const float s2 = csq[i2] - 2.f * d2;
        if (s2 > s1 || (s2 == s1 && i2 < i1)) { v1 = s2; i1 = i2; } else { v1 = s1; }
    }
    out[1 + n] = (float)i1;
    float s = v1;
#pragma unroll
    for (int mk = 1; mk <= 32; mk <<= 1) s += __shfl_xor(s, mk, 64);
    __shared__ float wsm[4];
    const int lane = threadIdx.x & 63, wd = threadIdx.x >> 6;
    if (lane == 0) wsm[wd] = s;
    __syncthreads();
    if (threadIdx.x == 0) sum2[blockIdx.x] = wsm[0] + wsm[1] + wsm[2] + wsm[3];
}

// ---------------- final: loss = lambda^2 * (sum e^2 + sum row maxima) --------
__global__ __launch_bounds__(256) void final_kernel(const float* __restrict__ e2s,
                                                    const float* __restrict__ sum2,
                                                    float* __restrict__ out) {
    float s = 0.f;
    for (int i = threadIdx.x; i < 2048; i += 256) s += e2s[i];
    for (int i = threadIdx.x; i < 512; i += 256) s += sum2[i];
#pragma unroll
    for (int mk = 1; mk <= 32; mk <<= 1) s += __shfl_xor(s, mk, 64);
    __shared__ float wsm[4];
    const int lane = threadIdx.x & 63, wd = threadIdx.x >> 6;
    if (lane == 0) wsm[wd] = s;
    __syncthreads();
    if (threadIdx.x == 0) out[0] = LM2 * (wsm[0] + wsm[1] + wsm[2] + wsm[3]);
}

extern "C" void kernel_launch(void* const* d_in, const int* in_sizes, int n_in,
                              void* d_out, int out_size, void* d_ws, size_t ws_size,
                              hipStream_t stream) {
    (void)n_in; (void)out_size; (void)ws_size;
    const float* E = (const float*)d_in[0];
    const float* Cg = (const float*)d_in[1];
    float* out = (float*)d_out;

    // ws (floats): csq[512] | e2s[2048] | sum2[512] | Cf16 (256KB) | partials (1MB)
    float* wsf = (float*)d_ws;
    float* csq = wsf;
    float* e2s = wsf + 512;
    float* sum2 = wsf + 2560;
    unsigned short* Cf = (unsigned short*)(wsf + 3072);
    uint2* partials = (uint2*)(wsf + 3072 + 65536);

    const int N = in_sizes[0] / ND;  // 131072
    const int nblk = N >> 8;         // 512 blocks of 256 rows (one generation)

    prep_kernel<<<NK, 64, 0, stream>>>(Cg, csq, Cf);
    kmeans_mfma<<<nblk, 256, 0, stream>>>(E, Cf, csq, partials, e2s);
    combine_kernel<<<N / 256, 256, 0, stream>>>(partials, csq, E, Cg, out, sum2);
    final_kernel<<<1, 256, 0, stream>>>(e2s, sum2, out);
}

// Round 19
// 90.284 us; speedup vs baseline: 2.3185x; 2.3185x over previous
//
#include <hip/hip_runtime.h>

#define ND 256       // embedding dim
#define NK 512       // centroids
#define LM2 0.0625f  // lambda^2
#define DELTA 0.25f  // approx top-2 gap below this -> exact fp32 rescore

typedef _Float16 f16x8 __attribute__((ext_vector_type(8)));
typedef float f32x4 __attribute__((ext_vector_type(4)));
typedef unsigned short u16x8 __attribute__((ext_vector_type(8)));
typedef unsigned short u16x4 __attribute__((ext_vector_type(4)));

// async 16B global->LDS (zero VGPR staging). LDS dest is wave-uniform base
// (HW adds lane*16); global src is per-lane.
#define GLD16(GSRC, LDST)                                                      \
    __builtin_amdgcn_global_load_lds(                                         \
        (const __attribute__((address_space(1))) void*)(GSRC),                \
        (__attribute__((address_space(3))) void*)(LDST), 16, 0, 0)

// ---------------- prep: csq[k] + fp16 centroids in per-64col-panel frag order --
// Cf layout: [panel 8][krow 32][col 64][8], krow = (d>>5)*4 + ((d>>3)&3).
// UNCHANGED from r13-r17 (verified): the same 16B granule now serves as the
// MFMA A-operand fragment (16 centroids x 32 k), byte-identical reads.
__global__ __launch_bounds__(64) void prep_kernel(const float* __restrict__ Cg,
                                                  float* __restrict__ csq,
                                                  unsigned short* __restrict__ Cf) {
    const int k = blockIdx.x, lane = threadIdx.x;
    float4 v = *(const float4*)(Cg + (size_t)k * ND + lane * 4);
    float s = v.x * v.x + v.y * v.y + v.z * v.z + v.w * v.w;
#pragma unroll
    for (int m = 1; m <= 32; m <<= 1) s += __shfl_xor(s, m, 64);
    if (lane == 0) csq[k] = s;
    u16x4 h;
    h[0] = __builtin_bit_cast(unsigned short, (_Float16)v.x);
    h[1] = __builtin_bit_cast(unsigned short, (_Float16)v.y);
    h[2] = __builtin_bit_cast(unsigned short, (_Float16)v.z);
    h[3] = __builtin_bit_cast(unsigned short, (_Float16)v.w);
    const int panel = k >> 6, col = k & 63;
    const int krow = (lane >> 3) * 4 + ((lane >> 1) & 3);  // d0 = lane*4
    const size_t idx = ((size_t)panel << 14) + ((((size_t)krow << 6) + col) << 3) + ((lane & 1) << 2);
    *(u16x4*)(Cf + idx) = h;
}

// ---------------- main: OPERAND-SWAPPED MFMA, 32 rows/wave, 2x B-reuse -------
// grid 512 x 512 thr: 256 rows/block (8 waves x 32), ONE generation (2 bl/CU).
// D[centroid][row] = mfma(A=centroid-frag, B=E-frag): both fragment layouts are
// byte-identical to the session-verified reads. Each centroid ds_read_b128
// feeds TWO MFMAs (E row-groups g=0,1) -> chip LDS volume 1.05 GB (20.5 us
// floor, half of r13). Per-lane state: Ef[2][8]=64 + acc 8 + keys 4 + csp 4
// ~= 100 regs < 128 cap (the swap is what shrinks acc/keys 4x vs r17).
// Per-wave output rows are FINAL (all 512 cols) -> partials = 1 uint2/row.
__global__ __launch_bounds__(512, 2) void kmeans_mfma(
    const float* __restrict__ E, const unsigned short* __restrict__ Cf,
    const float* __restrict__ csq, uint2* __restrict__ partials,
    float* __restrict__ e2s) {
    __shared__ unsigned short Bbuf[2][16384];  // 2 x 32 KB

    const int tid = threadIdx.x;
    const int lane = tid & 63, wid = tid >> 6;  // wid 0..7
    const int l15 = lane & 15, l4 = lane >> 4;
    const int rowbase = blockIdx.x << 8;  // 256 rows/block
    const int wrow = rowbase + wid * 32;  // 32 rows/wave

    // ---- issue panel 0 staging (flies during E-load); 4 slots per wave ----
#pragma unroll
    for (int i = 0; i < 4; ++i)
        GLD16(Cf + (((size_t)(wid * 4 + i) * 64 + lane) << 3),
              &Bbuf[0][(size_t)(wid * 4 + i) << 9]);

    // ---- E load: rows wrow+g*16+l15 (g=0,1), chunks of 4 ks (r13-proven) ----
    f16x8 Ef[2][8];  // [g][ks], 64 VGPR; B-frag: col=l15(row), k=l4*8 (verified)
    float e2 = 0.f;
#pragma unroll
    for (int g = 0; g < 2; ++g) {
        const float* ap = E + (size_t)(wrow + g * 16 + l15) * ND + l4 * 8;
#pragma unroll
        for (int half = 0; half < 2; ++half) {
            float4 t[8];
#pragma unroll
            for (int q = 0; q < 4; ++q) {
                t[q * 2]     = *(const float4*)(ap + (half * 4 + q) * 32);
                t[q * 2 + 1] = *(const float4*)(ap + (half * 4 + q) * 32 + 4);
            }
#pragma unroll
            for (int q = 0; q < 4; ++q) {
                float4 v0 = t[q * 2], v1 = t[q * 2 + 1];
                e2 += v0.x * v0.x + v0.y * v0.y + v0.z * v0.z + v0.w * v0.w +
                      v1.x * v1.x + v1.y * v1.y + v1.z * v1.z + v1.w * v1.w;
                u16x8 h;
                h[0] = __builtin_bit_cast(unsigned short, (_Float16)v0.x);
                h[1] = __builtin_bit_cast(unsigned short, (_Float16)v0.y);
                h[2] = __builtin_bit_cast(unsigned short, (_Float16)v0.z);
                h[3] = __builtin_bit_cast(unsigned short, (_Float16)v0.w);
                h[4] = __builtin_bit_cast(unsigned short, (_Float16)v1.x);
                h[5] = __builtin_bit_cast(unsigned short, (_Float16)v1.y);
                h[6] = __builtin_bit_cast(unsigned short, (_Float16)v1.z);
                h[7] = __builtin_bit_cast(unsigned short, (_Float16)v1.w);
                Ef[g][half * 4 + q] = __builtin_bit_cast(f16x8, h);
            }
        }
    }

    unsigned k1[2] = {0u, 0u}, k2[2] = {0u, 0u};  // per row-group top-2 keys

#pragma unroll 1
    for (int p = 0; p < 8; ++p) {
        __syncthreads();  // drains own vmcnt: panel p staged; buf[(p+1)&1] free
        if (p < 7) {      // issue next panel (lands during this panel's compute)
            const unsigned short* gsrc = Cf + ((size_t)(p + 1) << 14);
            unsigned short* ldst = (unsigned short*)Bbuf[(p + 1) & 1];
#pragma unroll
            for (int i = 0; i < 4; ++i)
                GLD16(gsrc + (((size_t)(wid * 4 + i) * 64 + lane) << 3),
                      &ldst[(size_t)(wid * 4 + i) << 9]);
        }
        const unsigned short* cur = Bbuf[p & 1];
        // 4 centroid 16-tiles per panel; each A-frag read feeds BOTH row-groups
#pragma unroll
        for (int n = 0; n < 4; ++n) {
            // csq for this lane's 4 centroids (L1-resident 2KB table)
            const float4 csp = *(const float4*)(csq + (p << 6) + n * 16 + l4 * 4);
            f32x4 a0 = {}, a1 = {};
#pragma unroll
            for (int ks = 0; ks < 8; ++ks) {
                const u16x8 bfr =
                    *(const u16x8*)&cur[(size_t)((((ks << 2) + l4) << 6) + n * 16 + l15) << 3];
                const f16x8 cf = __builtin_bit_cast(f16x8, bfr);  // A-frag: 16 centroids x 32k
                a0 = __builtin_amdgcn_mfma_f32_16x16x32_f16(cf, Ef[0][ks], a0, 0, 0, 0);
                a1 = __builtin_amdgcn_mfma_f32_16x16x32_f16(cf, Ef[1][ks], a1, 0, 0, 0);
            }
            // fold: lane holds centroids c = p*64+n*16+l4*4+j for row (l15, g)
            const unsigned kbase = (unsigned)(NK - 1 - ((p << 6) + n * 16 + l4 * 4));
            const float cs[4] = {csp.x, csp.y, csp.z, csp.w};
#pragma unroll
            for (int g = 0; g < 2; ++g) {
                const f32x4 ag = g ? a1 : a0;
#pragma unroll
                for (int j = 0; j < 4; ++j) {
                    const float s = fmaf(-2.f, ag[j], cs[j]);
                    const unsigned b = __builtin_bit_cast(unsigned, s);
                    const unsigned mono = b ^ ((unsigned)((int)b >> 31) | 0x80000000u);
                    const unsigned key = (mono & 0xFFFFFE00u) | (kbase - (unsigned)j);
                    const unsigned mn = min(k1[g], key);
                    k1[g] = max(k1[g], key);
                    k2[g] = max(k2[g], mn);
                }
            }
        }
    }

    // ---- merge across the 4 l4-lane-groups (rows are per-(l15,g)) ----
#pragma unroll
    for (int g = 0; g < 2; ++g) {
        unsigned a = k1[g], b2 = k2[g];
#pragma unroll
        for (int mk = 16; mk <= 32; mk <<= 1) {
            const unsigned oa = __shfl_xor(a, mk, 64);
            const unsigned ob = __shfl_xor(b2, mk, 64);
            const unsigned mn = min(a, oa);
            a = max(a, oa);
            b2 = max(max(b2, ob), mn);
        }
        if (l4 == 0) {
            uint2 o;
            o.x = a;
            o.y = b2;
            partials[wrow + g * 16 + l15] = o;  // FINAL top-2 for this row
        }
    }

    // ---- e2 partial (each element counted exactly once chip-wide) ----
#pragma unroll
    for (int mk = 1; mk <= 32; mk <<= 1) e2 += __shfl_xor(e2, mk, 64);
    if (lane == 0) e2s[blockIdx.x * 8 + wid] = e2;
}

// ---------------- combine: decode final top-2, rescore near-ties -------------
__global__ __launch_bounds__(256) void combine_kernel(
    const uint2* __restrict__ partials, const float* __restrict__ csq,
    const float* __restrict__ E, const float* __restrict__ Cg,
    float* __restrict__ out, float* __restrict__ sum2) {
    const int n = blockIdx.x * 256 + threadIdx.x;
    const uint2 kk = partials[n];
    const unsigned m1 = kk.x & 0xFFFFFE00u;
    float v1 = __builtin_bit_cast(float, (m1 & 0x80000000u) ? (m1 ^ 0x80000000u) : ~m1);
    int i1 = (int)(NK - 1) - (int)(kk.x & 511u);
    const unsigned m2 = kk.y & 0xFFFFFE00u;
    const float v2 = __builtin_bit_cast(float, (m2 & 0x80000000u) ? (m2 ^ 0x80000000u) : ~m2);
    const int i2 = (int)(NK - 1) - (int)(kk.y & 511u);

    if (v1 - v2 <= DELTA) {  // near-tie: exact fp32 rescore of both candidates
        const float* e = E + (size_t)n * ND;
        const float* c1p = Cg + (size_t)i1 * ND;
        const float* c2p = Cg + (size_t)i2 * ND;
        float d1 = 0.f, d2 = 0.f;
        for (int d = 0; d < ND; d += 4) {
            float4 ev = *(const float4*)(e + d);
            float4 cv1 = *(const float4*)(c1p + d);
            float4 cv2 = *(const float4*)(c2p + d);
            d1 += ev.x * cv1.x + ev.y * cv1.y + ev.z * cv1.z + ev.w * cv1.w;
            d2 += ev.x * cv2.x + ev.y * cv2.y + ev.z * cv2.z + ev.w * cv2.w;
        }
        const float s1 = csq[i1] - 2.f * d1;
        const float s2 = csq[i2] - 2.f * d2;
        if (s2 > s1 || (s2 == s1 && i2 < i1)) { v1 = s2; i1 = i2; } else { v1 = s1; }
    }
    out[1 + n] = (float)i1;
    float s = v1;
#pragma unroll
    for (int mk = 1; mk <= 32; mk <<= 1) s += __shfl_xor(s, mk, 64);
    __shared__ float wsm[4];
    const int lane = threadIdx.x & 63, wd = threadIdx.x >> 6;
    if (lane == 0) wsm[wd] = s;
    __syncthreads();
    if (threadIdx.x == 0) sum2[blockIdx.x] = wsm[0] + wsm[1] + wsm[2] + wsm[3];
}

// ---------------- final: loss = lambda^2 * (sum e^2 + sum row maxima) --------
__global__ __launch_bounds__(256) void final_kernel(const float* __restrict__ e2s,
                                                    const float* __restrict__ sum2,
                                                    float* __restrict__ out) {
    float s = 0.f;
    for (int i = threadIdx.x; i < 4096; i += 256) s += e2s[i];
    for (int i = threadIdx.x; i < 512; i += 256) s += sum2[i];
#pragma unroll
    for (int mk = 1; mk <= 32; mk <<= 1) s += __shfl_xor(s, mk, 64);
    __shared__ float wsm[4];
    const int lane = threadIdx.x & 63, wd = threadIdx.x >> 6;
    if (lane == 0) wsm[wd] = s;
    __syncthreads();
    if (threadIdx.x == 0) out[0] = LM2 * (wsm[0] + wsm[1] + wsm[2] + wsm[3]);
}

extern "C" void kernel_launch(void* const* d_in, const int* in_sizes, int n_in,
                              void* d_out, int out_size, void* d_ws, size_t ws_size,
                              hipStream_t stream) {
    (void)n_in; (void)out_size; (void)ws_size;
    const float* E = (const float*)d_in[0];
    const float* Cg = (const float*)d_in[1];
    float* out = (float*)d_out;

    // ws (floats): csq[512] | e2s[4096] | sum2[512] | Cf16 (256KB) | partials (1MB)
    float* wsf = (float*)d_ws;
    float* csq = wsf;
    float* e2s = wsf + 512;
    float* sum2 = wsf + 4608;
    unsigned short* Cf = (unsigned short*)(wsf + 5120);
    uint2* partials = (uint2*)(wsf + 5120 + 65536);

    const int N = in_sizes[0] / ND;  // 131072
    const int nblk = N >> 8;         // 512 blocks of 256 rows (one generation)

    prep_kernel<<<NK, 64, 0, stream>>>(Cg, csq, Cf);
    kmeans_mfma<<<nblk, 512, 0, stream>>>(E, Cf, csq, partials, e2s);
    combine_kernel<<<N / 256, 256, 0, stream>>>(partials, csq, E, Cg, out, sum2);
    final_kernel<<<1, 256, 0, stream>>>(e2s, sum2, out);
}